// Round 2
// baseline (108.593 us; speedup 1.0000x reference)
//
#include <hip/hip_runtime.h>

// Problem constants (reference: B=8, N=16384, F=128, P=28)
#define FDIM  128
#define PDIM  28
#define KPAD  896              // 28 p-steps * 32 padded q
#define MPTS  131072           // 8 * 16384 points

typedef _Float16 half8   __attribute__((ext_vector_type(8)));
typedef _Float16 half4v  __attribute__((ext_vector_type(4)));
typedef float    floatx4 __attribute__((ext_vector_type(4)));

// ---------------------------------------------------------------------------
// Prep: IF [F][28][28] fp32 -> IFt [F][KPAD] f16, k = p*32 + q, zero pad q>=28
// ---------------------------------------------------------------------------
__global__ __launch_bounds__(256) void prep_ift(const float* __restrict__ IF,
                                                _Float16* __restrict__ IFt) {
    int idx = blockIdx.x * 256 + threadIdx.x;     // 0 .. 128*896-1
    int f = idx / KPAD;
    int k = idx - f * KPAD;
    int p = k >> 5;
    int q = k & 31;
    float v = (q < PDIM) ? IF[f * (PDIM * PDIM) + p * PDIM + q] : 0.0f;
    IFt[idx] = (_Float16)v;
}

// ---------------------------------------------------------------------------
// Main: C[m,f] = sum_k W[m,k] * IFt[k,f],  W[m, p*32+q] = k0[m,p]*k1[m,q]
// Block: 128 points x 128 features, 4 waves each 128x32 (waves split features).
// Barrier-free K-loop: B fragments loaded directly from global (L2-resident),
// A fragments = (register-hoisted k1) * (k0 f16 from LDS, b64 over 4 K-steps).
// ---------------------------------------------------------------------------
__global__ __launch_bounds__(256, 3) void feats_kernel(
    const float* __restrict__ x,       // [MPTS][2]
    const float* __restrict__ sigma,   // [1] log lengthscale
    const _Float16* __restrict__ IFt,  // [FDIM][KPAD] f16
    float* __restrict__ out)           // [MPTS][FDIM]
{
    // k0: f16, stride 36 -> b64 reads at (m*72 + kk4*8): 18m mod 32 covers all
    //     32 banks exactly once across 16 m-rows; 4-quad broadcast is free.
    // k1: f16, stride 40 (80B) -> rows 16B-aligned, worst 2-way alias (free).
    __shared__ _Float16               k0s[128 * 36];
    __shared__ __align__(16) _Float16 k1s[128 * 40];

    const int tid  = threadIdx.x;
    const int lane = tid & 63;
    const int wave = tid >> 6;          // feature quarter: f in [wave*32, +32)
    const int ln15 = lane & 15;
    const int quad = lane >> 4;

    const float ls    = __expf(sigma[0]);
    const float inv   = 0.5f / (ls * ls);
    const float gstep = 0.998f / 27.0f;

    // ---- prologue: build k0 (threads 0..127) and k1 (threads 128..255) ----
    {
        const int ptl = tid & 127;
        const int ptg = blockIdx.x * 128 + ptl;
        if (tid < 128) {
            const float x0 = x[2 * ptg + 0];
            #pragma unroll
            for (int p = 0; p < PDIM; p++) {
                float d = (0.001f + p * gstep) - x0;
                k0s[ptl * 36 + p] = (_Float16)__expf(-inv * d * d);
            }
        } else {
            const float x1 = x[2 * ptg + 1];
            #pragma unroll
            for (int q = 0; q < PDIM; q++) {
                float d = (0.001f + q * gstep) - x1;
                k1s[ptl * 40 + q] = (_Float16)__expf(-inv * d * d);
            }
            #pragma unroll
            for (int q = PDIM; q < 32; q++)
                k1s[ptl * 40 + q] = (_Float16)0.0f;   // zero pad (quad 3 reads it)
        }
    }
    __syncthreads();   // only barrier in the kernel

    // ---- hoisted k1 A-fragments: A[m=lane&15][k=quad*8+j], m-tile mt*16 ----
    half8 k1f[8];
    #pragma unroll
    for (int mt = 0; mt < 8; mt++) {
        const int m = mt * 16 + ln15;
        k1f[mt] = *(const half8*)&k1s[m * 40 + quad * 8];
    }

    floatx4 acc[8][2];
    #pragma unroll
    for (int mt = 0; mt < 8; mt++) {
        acc[mt][0] = (floatx4){0.0f, 0.0f, 0.0f, 0.0f};
        acc[mt][1] = (floatx4){0.0f, 0.0f, 0.0f, 0.0f};
    }

    // ---- B global bases: lane reads IFt[f][kk*32 + quad*8 .. +7] (16B) ----
    const _Float16* gB0 = IFt + (size_t)(wave * 32 + ln15) * KPAD + quad * 8;
    const _Float16* gB1 = gB0 + 16 * KPAD;

    // One j-step: 2 global dwordx4 (immediate offsets) + 8 af + 16 MFMA.
    #define KSTEP(J)                                                          \
    {                                                                         \
        half8 bf0 = *(const half8*)(gB0 + kk4 * 128 + (J) * 32);              \
        half8 bf1 = *(const half8*)(gB1 + kk4 * 128 + (J) * 32);              \
        _Pragma("unroll")                                                     \
        for (int mt = 0; mt < 8; mt++) {                                      \
            const half8 af = k1f[mt] * k0v[mt][(J)];                          \
            acc[mt][0] = __builtin_amdgcn_mfma_f32_16x16x32_f16(              \
                af, bf0, acc[mt][0], 0, 0, 0);                                \
            acc[mt][1] = __builtin_amdgcn_mfma_f32_16x16x32_f16(              \
                af, bf1, acc[mt][1], 0, 0, 0);                                \
        }                                                                     \
    }

    #pragma unroll 1
    for (int kk4 = 0; kk4 < 7; kk4++) {           // 7 groups of 4 K-steps
        half4v k0v[8];                             // k0[m][kk4*4 .. +3]
        #pragma unroll
        for (int mt = 0; mt < 8; mt++) {
            const int m = mt * 16 + ln15;
            k0v[mt] = *(const half4v*)&k0s[m * 36 + kk4 * 4];
        }
        KSTEP(0)
        KSTEP(1)
        KSTEP(2)
        KSTEP(3)
    }
    #undef KSTEP

    // ---- epilogue: C/D layout col = lane&15 (feature), row = quad*4 + r ----
    #pragma unroll
    for (int mt = 0; mt < 8; mt++) {
        const int row0 = blockIdx.x * 128 + mt * 16 + quad * 4;
        #pragma unroll
        for (int nt = 0; nt < 2; nt++) {
            const int col = wave * 32 + nt * 16 + ln15;
            float* op = out + (size_t)row0 * FDIM + col;
            #pragma unroll
            for (int r = 0; r < 4; r++)
                __builtin_nontemporal_store(acc[mt][nt][r], op + (size_t)r * FDIM);
        }
    }
}

// ---------------------------------------------------------------------------
extern "C" void kernel_launch(void* const* d_in, const int* in_sizes, int n_in,
                              void* d_out, int out_size, void* d_ws, size_t ws_size,
                              hipStream_t stream) {
    const float* x     = (const float*)d_in[0];   // [8,16384,2]
    const float* sigma = (const float*)d_in[1];   // [1]
    const float* IF    = (const float*)d_in[2];   // [128,28,28]
    float* out = (float*)d_out;                   // [8,16384,128] fp32

    // d_ws: IFt f16 [128][896] = 229376 bytes
    _Float16* IFt = (_Float16*)d_ws;

    prep_ift<<<(FDIM * KPAD) / 256, 256, 0, stream>>>(IF, IFt);          // 448 blocks
    feats_kernel<<<MPTS / 128, 256, 0, stream>>>(x, sigma, IFt, out);    // 1024 blocks
}